// Round 9
// baseline (36.526 us; speedup 1.0000x reference)
//
#include <hip/hip_runtime.h>
#include <math.h>

#define MG 16384
#define NFOC (3 * MG)
#define NNXT (4 * MG)

typedef float f32x4 __attribute__((ext_vector_type(4)));
typedef short s16x8 __attribute__((ext_vector_type(8)));

// ws layout: hB4 f32[4096] at byte 0 (layout [h>>2][l][h&3]); bf16 weight frags
// (ushort) at byte 16384. per-MLP bases in SHORTS within wt region:
#define WT_STOP 0
#define WT_FATT 4096
#define WT_NFRAG 12288
#define WT_NFATT 20480
#define WT_BOND 36864
#define WT_TOTAL 53248  // shorts

#define SW(r, b) ((b) ^ (((r) & 7) << 4))

// NOTE: DPP 16-lane reduction (R5/R7) is QUARANTINED (absmax 11.58).
// v_cvt_pk_bf16_f32 inline asm also quarantined. __shfl_xor is proven.

__device__ __forceinline__ float lrelu(float x) { return x > 0.f ? x : 0.01f * x; }

__device__ __forceinline__ unsigned short f2bf(float f) {
  union { float f; unsigned u; } a;
  a.f = f;
  unsigned u = a.u;
  unsigned r = (u + 0x7fffu + ((u >> 16) & 1u)) >> 16;  // RNE
  return (unsigned short)r;
}

// ---------------- prep: hB4 (f32) + weight transpose/convert to B-frag layout
__global__ void prep(const float* __restrict__ flf,
                     const float* __restrict__ stopW1,
                     const float* __restrict__ fattW1,
                     const float* __restrict__ nfragW1,
                     const float* __restrict__ nfattW1,
                     const float* __restrict__ bondW1,
                     float* __restrict__ hB4, unsigned short* __restrict__ wt) {
  int b = blockIdx.x, t = threadIdx.x;
  if (b < 16) {  // hB[h,l] = sum_k flf[l][k]*nfragW1[(128+k)*64+h]
    int l = b * 4 + (t >> 6), h = t & 63;
    float acc = 0.f;
#pragma unroll 8
    for (int k = 0; k < 64; ++k)
      acc = fmaf(flf[l * 64 + k], nfragW1[(128 + k) * 64 + h], acc);
    hB4[(h >> 2) * 256 + l * 4 + (h & 3)] = acc;
  } else {
    int e = (b - 16) * 256 + t;  // 0..53247
    if (e < WT_TOTAL) {
      int k_all = e >> 6, col = e & 63;
      const float* src;
      int k, base;
      if (k_all < 64) { src = stopW1; k = k_all; base = WT_STOP; }
      else if (k_all < 192) { src = fattW1; k = k_all - 64; base = WT_FATT; }
      else if (k_all < 320) { src = nfragW1; k = k_all - 192; base = WT_NFRAG; }
      else if (k_all < 576) { src = nfattW1; k = k_all - 320; base = WT_NFATT; }
      else { src = bondW1; k = k_all - 576; base = WT_BOND; }
      int kt = k >> 5, kg = (k >> 3) & 3, ki = k & 7;
      wt[base + (((kt * 4 + kg) * 64 + col) << 3) + ki] = f2bf(src[k * 64 + col]);
    }
  }
}

// stage one gathered f32 row chunk (4 floats) into a swizzled bf16 LDS tile
__device__ __forceinline__ float4 stage_row(char* tileBase, int r, int c4,
                                            const float* srcRow) {
  float4 v = *((const float4*)srcRow + c4);
  unsigned long long pk =
      (unsigned long long)f2bf(v.x) | ((unsigned long long)f2bf(v.y) << 16) |
      ((unsigned long long)f2bf(v.z) << 32) | ((unsigned long long)f2bf(v.w) << 48);
  *(unsigned long long*)(tileBase + r * 128 + SW(r, c4 * 8)) = pk;
  return v;
}

__device__ __forceinline__ s16x8 ldA(const char* tile, int ktLocal, int lane) {
  int r = lane & 15, kg = lane >> 4;
  int b = ktLocal * 64 + kg * 16;
  return *(const s16x8*)(tile + r * 128 + SW(r, b));
}

__device__ __forceinline__ s16x8 ldB(const unsigned short* wt, int base,
                                     int ktGlobal, int kg, int col) {
  return *(const s16x8*)(wt + base + (((ktGlobal * 4 + kg) * 64 + col) << 3));
}

// 4 block types x 1024 M-tiles, interleaved (type = bid & 3):
// A={stop,fatt}, B={nfatt}, C={bond}, D={nfrag hA+einsum}.
// Layer-2 heads use TRANSPOSED MFMA (swap A/B operands -> C[h][m]):
// reduction over h = 4 in-lane FMAs + 2 shuffles (vs 16 shuffles).
__global__ __launch_bounds__(256, 8) void decoder_main(
    const float* __restrict__ flf, const float* __restrict__ flnf,
    const float* __restrict__ gsf, const float* __restrict__ hpart,
    const float* __restrict__ hfoc,
    const int* __restrict__ nidx, const int* __restrict__ faidx,
    const int* __restrict__ naidx,
    const float* __restrict__ stopB1, const float* __restrict__ stopW2,
    const float* __restrict__ stopB2,
    const float* __restrict__ fattB1, const float* __restrict__ fattW2,
    const float* __restrict__ fattB2,
    const float* __restrict__ nfragB1, const float* __restrict__ nfragW2,
    const float* __restrict__ nfragB2,
    const float* __restrict__ nfattB1, const float* __restrict__ nfattW2,
    const float* __restrict__ nfattB2,
    const float* __restrict__ bondB1, const float* __restrict__ bondW2,
    const float* __restrict__ bondB2,
    const float* __restrict__ hB4, const unsigned short* __restrict__ wt,
    float* __restrict__ out) {
  const int tid = threadIdx.x;
  const int lane = tid & 63;
  const int w = tid >> 6;             // wave: owns h strip [16w, 16w+16)
  const int kg = lane >> 4;           // k-group 0..3
  const int cl = lane & 15;
  const int col = w * 16 + cl;        // weight column for ldB
  const int hb = w * 16 + kg * 4;     // this lane's 4 h indices (transposed C)
  const int bid = (int)blockIdx.x;
  const int type = bid & 3;
  const int m0 = (bid >> 2) * 16;

  float* o_stop = out;                 // [MG]
  float* o_nfrag = out + MG;           // [MG,64]
  float* o_fatt = out + MG + MG * 64;  // [3*MG]
  float* o_nfatt = o_fatt + NFOC;      // [4*MG]
  float* o_bond = o_nfatt + NNXT;      // [MG,4]

  __shared__ char tiles[14336];     // up to 7 bf16 tiles (16 x 128B, swizzled)
  __shared__ float hAl[16][68];     // type D only
  __shared__ float scp[4][4][16];   // [wave][slot][graph] partial h-sums
  char* TG = tiles;                 // xg
  char* TP = tiles + 2048;          // xp
  char* T2 = tiles + 4096;          // A: hf[3] | B/C: xf
  char* T3 = tiles + 6144;          // B: na[4] | C: pooled

  // ---------------- stage (per type) ----------------
  {
    int r = tid >> 4, c4 = tid & 15;
    int m = m0 + r;
    stage_row(TG, r, c4, gsf + (size_t)m * 64);
    if (type == 0) {
#pragma unroll
      for (int rr = 0; rr < 3; ++rr)
        stage_row(T2 + rr * 2048, r, c4, hfoc + (size_t)(m + rr * MG) * 64);
    } else if (type == 1) {
      stage_row(TP, r, c4, hpart + (size_t)faidx[m] * 64);
      stage_row(T2, r, c4, flf + (size_t)nidx[m] * 64);
#pragma unroll
      for (int rr = 0; rr < 4; ++rr)
        stage_row(T3 + rr * 2048, r, c4, flnf + (size_t)naidx[m + rr * MG] * 64);
    } else if (type == 2) {
      stage_row(TP, r, c4, hpart + (size_t)faidx[m] * 64);
      stage_row(T2, r, c4, flf + (size_t)nidx[m] * 64);
      float px = 0.f, py = 0.f, pz = 0.f, pw = 0.f;
#pragma unroll
      for (int rr = 0; rr < 4; ++rr) {
        float4 v = *((const float4*)(flnf + (size_t)naidx[m + rr * MG] * 64) + c4);
        px += v.x; py += v.y; pz += v.z; pw += v.w;
      }
      unsigned long long pk = (unsigned long long)f2bf(0.25f * px) |
                              ((unsigned long long)f2bf(0.25f * py) << 16) |
                              ((unsigned long long)f2bf(0.25f * pz) << 32) |
                              ((unsigned long long)f2bf(0.25f * pw) << 48);
      *(unsigned long long*)(T3 + r * 128 + SW(r, c4 * 8)) = pk;
    } else {
      stage_row(TP, r, c4, hpart + (size_t)faidx[m] * 64);
    }
  }
  __syncthreads();

#define MFMA(a, b, c) __builtin_amdgcn_mfma_f32_16x16x32_bf16(a, b, c, 0, 0, 0)
// transposed-head reduce: v holds per-lane partial; sum over kg groups.
#define REDT(v, slot)                                                      \
  {                                                                        \
    v += __shfl_xor(v, 16);                                                \
    v += __shfl_xor(v, 32);                                                \
    if (lane < 16) scp[w][slot][lane] = v;                                 \
  }

  if (type == 0) {
    // ---------------- stop (K=64) -> slot 0 [transposed] ----------------
    {
      f32x4 acc = *(const f32x4*)(stopB1 + hb);
      acc = MFMA(ldB(wt, WT_STOP, 0, kg, col), ldA(TG, 0, lane), acc);
      acc = MFMA(ldB(wt, WT_STOP, 1, kg, col), ldA(TG, 1, lane), acc);
      f32x4 w2 = *(const f32x4*)(stopW2 + hb);
      float v = 0.f;
#pragma unroll
      for (int i = 0; i < 4; ++i) v = fmaf(lrelu(acc[i]), w2[i], v);
      REDT(v, 0);
    }
    // ---------------- fatt (shared K=64 + 3 x K=64) -> slots 1..3 ----------
    {
      f32x4 aS = *(const f32x4*)(fattB1 + hb);
      aS = MFMA(ldB(wt, WT_FATT, 0, kg, col), ldA(TG, 0, lane), aS);
      aS = MFMA(ldB(wt, WT_FATT, 1, kg, col), ldA(TG, 1, lane), aS);
      f32x4 w2 = *(const f32x4*)(fattW2 + hb);
#pragma unroll
      for (int rr = 0; rr < 3; ++rr) {
        f32x4 acc = aS;
        acc = MFMA(ldB(wt, WT_FATT, 2, kg, col), ldA(T2 + rr * 2048, 0, lane), acc);
        acc = MFMA(ldB(wt, WT_FATT, 3, kg, col), ldA(T2 + rr * 2048, 1, lane), acc);
        float v = 0.f;
#pragma unroll
        for (int i = 0; i < 4; ++i) v = fmaf(lrelu(acc[i]), w2[i], v);
        REDT(v, 1 + rr);
      }
    }
    __syncthreads();
    if (tid < 32) {
      int mm = tid & 15;
      int m = m0 + mm;
      if (tid < 16) {
        float s = scp[0][0][mm] + scp[1][0][mm] + scp[2][0][mm] + scp[3][0][mm];
        o_stop[m] = s + stopB2[0];
      } else {
        float sc[3];
#pragma unroll
        for (int r = 0; r < 3; ++r)
          sc[r] = scp[0][1 + r][mm] + scp[1][1 + r][mm] + scp[2][1 + r][mm] +
                  scp[3][1 + r][mm] + fattB2[0];
        float mx = fmaxf(fmaxf(sc[0], sc[1]), sc[2]);
        float e0 = expf(sc[0] - mx), e1 = expf(sc[1] - mx), e2 = expf(sc[2] - mx);
        float inv = 1.f / (e0 + e1 + e2);
        o_fatt[m] = e0 * inv;
        o_fatt[m + MG] = e1 * inv;
        o_fatt[m + 2 * MG] = e2 * inv;
      }
    }
  } else if (type == 1) {
    // ---------------- nfatt (shared K=192 + 4 x K=64) [transposed] ---------
    {
      f32x4 aS = *(const f32x4*)(nfattB1 + hb);
      aS = MFMA(ldB(wt, WT_NFATT, 0, kg, col), ldA(TG, 0, lane), aS);
      aS = MFMA(ldB(wt, WT_NFATT, 1, kg, col), ldA(TG, 1, lane), aS);
      aS = MFMA(ldB(wt, WT_NFATT, 2, kg, col), ldA(TP, 0, lane), aS);
      aS = MFMA(ldB(wt, WT_NFATT, 3, kg, col), ldA(TP, 1, lane), aS);
      aS = MFMA(ldB(wt, WT_NFATT, 4, kg, col), ldA(T2, 0, lane), aS);
      aS = MFMA(ldB(wt, WT_NFATT, 5, kg, col), ldA(T2, 1, lane), aS);
      f32x4 w2 = *(const f32x4*)(nfattW2 + hb);
#pragma unroll
      for (int rr = 0; rr < 4; ++rr) {
        f32x4 acc = aS;
        acc = MFMA(ldB(wt, WT_NFATT, 6, kg, col), ldA(T3 + rr * 2048, 0, lane), acc);
        acc = MFMA(ldB(wt, WT_NFATT, 7, kg, col), ldA(T3 + rr * 2048, 1, lane), acc);
        float v = 0.f;
#pragma unroll
        for (int i = 0; i < 4; ++i) v = fmaf(lrelu(acc[i]), w2[i], v);
        REDT(v, rr);
      }
    }
    __syncthreads();
    if (tid < 16) {
      int m = m0 + tid;
      float sc[4];
#pragma unroll
      for (int r = 0; r < 4; ++r)
        sc[r] = scp[0][r][tid] + scp[1][r][tid] + scp[2][r][tid] +
                scp[3][r][tid] + nfattB2[0];
      float mx = fmaxf(fmaxf(sc[0], sc[1]), fmaxf(sc[2], sc[3]));
      float e0 = expf(sc[0] - mx), e1 = expf(sc[1] - mx), e2 = expf(sc[2] - mx),
            e3 = expf(sc[3] - mx);
      float inv = 1.f / (e0 + e1 + e2 + e3);
      o_nfatt[m] = e0 * inv;
      o_nfatt[m + MG] = e1 * inv;
      o_nfatt[m + 2 * MG] = e2 * inv;
      o_nfatt[m + 3 * MG] = e3 * inv;
    }
  } else if (type == 2) {
    // ---------------- bond (K=256) [transposed] ----------------
    {
      f32x4 acc = *(const f32x4*)(bondB1 + hb);
      acc = MFMA(ldB(wt, WT_BOND, 0, kg, col), ldA(TG, 0, lane), acc);
      acc = MFMA(ldB(wt, WT_BOND, 1, kg, col), ldA(TG, 1, lane), acc);
      acc = MFMA(ldB(wt, WT_BOND, 2, kg, col), ldA(TP, 0, lane), acc);
      acc = MFMA(ldB(wt, WT_BOND, 3, kg, col), ldA(TP, 1, lane), acc);
      acc = MFMA(ldB(wt, WT_BOND, 4, kg, col), ldA(T2, 0, lane), acc);
      acc = MFMA(ldB(wt, WT_BOND, 5, kg, col), ldA(T2, 1, lane), acc);
      acc = MFMA(ldB(wt, WT_BOND, 6, kg, col), ldA(T3, 0, lane), acc);
      acc = MFMA(ldB(wt, WT_BOND, 7, kg, col), ldA(T3, 1, lane), acc);
      float l4[4];
      f32x4 bw[4];
#pragma unroll
      for (int i = 0; i < 4; ++i) {
        l4[i] = lrelu(acc[i]);
        bw[i] = *(const f32x4*)(bondW2 + (hb + i) * 4);
      }
#pragma unroll
      for (int o = 0; o < 4; ++o) {
        float v = 0.f;
#pragma unroll
        for (int i = 0; i < 4; ++i) v = fmaf(l4[i], bw[i][o], v);
        REDT(v, o);
      }
    }
    __syncthreads();
    if (tid < 16) {
      int m = m0 + tid;
#pragma unroll
      for (int o = 0; o < 4; ++o) {
        float s = scp[0][o][tid] + scp[1][o][tid] + scp[2][o][tid] +
                  scp[3][o][tid];
        o_bond[m * 4 + o] = s + bondB2[o];
      }
    }
  } else {
    // ---------------- nfrag hA (K=128, normal orientation) + einsum --------
    {
      float b1 = nfragB1[col];
      f32x4 acc = {b1, b1, b1, b1};
      acc = MFMA(ldA(TG, 0, lane), ldB(wt, WT_NFRAG, 0, kg, col), acc);
      acc = MFMA(ldA(TG, 1, lane), ldB(wt, WT_NFRAG, 1, kg, col), acc);
      acc = MFMA(ldA(TP, 0, lane), ldB(wt, WT_NFRAG, 2, kg, col), acc);
      acc = MFMA(ldA(TP, 1, lane), ldB(wt, WT_NFRAG, 3, kg, col), acc);
#pragma unroll
      for (int i = 0; i < 4; ++i) hAl[kg * 4 + i][col] = acc[i];
    }
    __syncthreads();
    // out[m,l] = sum_h lrelu(hA[m,h]+hB[h,l])*w2[h]; lane = l
    {
      float accL[4] = {0.f, 0.f, 0.f, 0.f};
#pragma unroll
      for (int hg = 0; hg < 16; ++hg) {
        f32x4 hb4v = *(const f32x4*)(hB4 + hg * 256 + lane * 4);
        f32x4 w2v = *(const f32x4*)(nfragW2 + hg * 4);
#pragma unroll
        for (int mi = 0; mi < 4; ++mi) {
          f32x4 ha = *(const f32x4*)(&hAl[w * 4 + mi][hg * 4]);  // uniform b128
#pragma unroll
          for (int j = 0; j < 4; ++j) {
            float x = ha[j] + hb4v[j];
            accL[mi] = fmaf(fmaxf(x, 0.01f * x), w2v[j], accL[mi]);
          }
        }
      }
#pragma unroll
      for (int mi = 0; mi < 4; ++mi)
        o_nfrag[(size_t)(m0 + w * 4 + mi) * 64 + lane] = accL[mi] + nfragB2[0];
    }
  }
}

extern "C" void kernel_launch(void* const* d_in, const int* in_sizes, int n_in,
                              void* d_out, int out_size, void* d_ws, size_t ws_size,
                              hipStream_t stream) {
  const float* flf = (const float*)d_in[0];
  const float* flnf = (const float*)d_in[1];
  const float* gsf = (const float*)d_in[2];
  const float* hpart = (const float*)d_in[3];
  const float* hfoc = (const float*)d_in[4];
  const int* nidx = (const int*)d_in[5];
  const int* faidx = (const int*)d_in[9];
  const int* naidx = (const int*)d_in[10];

  const float* stopW1 = (const float*)d_in[13];
  const float* stopB1 = (const float*)d_in[14];
  const float* stopW2 = (const float*)d_in[15];
  const float* stopB2 = (const float*)d_in[16];
  const float* fattW1 = (const float*)d_in[17];
  const float* fattB1 = (const float*)d_in[18];
  const float* fattW2 = (const float*)d_in[19];
  const float* fattB2 = (const float*)d_in[20];
  const float* nfragW1 = (const float*)d_in[21];
  const float* nfragB1 = (const float*)d_in[22];
  const float* nfragW2 = (const float*)d_in[23];
  const float* nfragB2 = (const float*)d_in[24];
  const float* nfattW1 = (const float*)d_in[25];
  const float* nfattB1 = (const float*)d_in[26];
  const float* nfattW2 = (const float*)d_in[27];
  const float* nfattB2 = (const float*)d_in[28];
  const float* bondW1 = (const float*)d_in[29];
  const float* bondB1 = (const float*)d_in[30];
  const float* bondW2 = (const float*)d_in[31];
  const float* bondB2 = (const float*)d_in[32];

  float* hB4 = (float*)d_ws;                                     // 16 KB
  unsigned short* wtb = (unsigned short*)((char*)d_ws + 16384);  // 104 KB

  prep<<<16 + (WT_TOTAL + 255) / 256, 256, 0, stream>>>(
      flf, stopW1, fattW1, nfragW1, nfattW1, bondW1, hB4, wtb);

  decoder_main<<<4 * 1024, 256, 0, stream>>>(
      flf, flnf, gsf, hpart, hfoc, nidx, faidx, naidx,
      stopB1, stopW2, stopB2,
      fattB1, fattW2, fattB2,
      nfragB1, nfragW2, nfragB2,
      nfattB1, nfattW2, nfattB2,
      bondB1, bondW2, bondB2,
      hB4, wtb, (float*)d_out);
}

// Round 10
// 26.704 us; speedup vs baseline: 1.3678x; 1.3678x over previous
//
#include <hip/hip_runtime.h>
#include <math.h>

#define MG 16384
#define NFOC (3 * MG)
#define NNXT (4 * MG)

typedef float f32x4 __attribute__((ext_vector_type(4)));
typedef short s16x8 __attribute__((ext_vector_type(8)));

// ws layout: hB4 f32[4096] at byte 0 (layout [h>>2][l][h&3]); bf16 weight frags
// (ushort) at byte 16384. per-MLP bases in SHORTS within wt region:
#define WT_STOP 0
#define WT_FATT 4096
#define WT_NFRAG 12288
#define WT_NFATT 20480
#define WT_BOND 36864
#define WT_TOTAL 53248  // shorts

#define SW(r, b) ((b) ^ (((r) & 7) << 4))

// NOTE: DPP 16-lane reduction (R5/R7) is QUARANTINED (absmax 11.58).
// v_cvt_pk_bf16_f32 inline asm also quarantined. __shfl_xor is proven.
// R9 lesson: block-type interleaving (type = bid & 3) thrashes per-CU L1
// with the union of all weight sets -> contiguous type ranges only.

__device__ __forceinline__ float lrelu(float x) { return x > 0.f ? x : 0.01f * x; }

__device__ __forceinline__ unsigned short f2bf(float f) {
  union { float f; unsigned u; } a;
  a.f = f;
  unsigned u = a.u;
  unsigned r = (u + 0x7fffu + ((u >> 16) & 1u)) >> 16;  // RNE
  return (unsigned short)r;
}

// ---------------- prep: hB4 (f32) + weight transpose/convert to B-frag layout
__global__ void prep(const float* __restrict__ flf,
                     const float* __restrict__ stopW1,
                     const float* __restrict__ fattW1,
                     const float* __restrict__ nfragW1,
                     const float* __restrict__ nfattW1,
                     const float* __restrict__ bondW1,
                     float* __restrict__ hB4, unsigned short* __restrict__ wt) {
  int b = blockIdx.x, t = threadIdx.x;
  if (b < 16) {  // hB[h,l] = sum_k flf[l][k]*nfragW1[(128+k)*64+h]
    int l = b * 4 + (t >> 6), h = t & 63;
    float acc = 0.f;
#pragma unroll 8
    for (int k = 0; k < 64; ++k)
      acc = fmaf(flf[l * 64 + k], nfragW1[(128 + k) * 64 + h], acc);
    hB4[(h >> 2) * 256 + l * 4 + (h & 3)] = acc;
  } else {
    int e = (b - 16) * 256 + t;  // 0..53247
    if (e < WT_TOTAL) {
      int k_all = e >> 6, col = e & 63;
      const float* src;
      int k, base;
      if (k_all < 64) { src = stopW1; k = k_all; base = WT_STOP; }
      else if (k_all < 192) { src = fattW1; k = k_all - 64; base = WT_FATT; }
      else if (k_all < 320) { src = nfragW1; k = k_all - 192; base = WT_NFRAG; }
      else if (k_all < 576) { src = nfattW1; k = k_all - 320; base = WT_NFATT; }
      else { src = bondW1; k = k_all - 576; base = WT_BOND; }
      int kt = k >> 5, kg = (k >> 3) & 3, ki = k & 7;
      wt[base + (((kt * 4 + kg) * 64 + col) << 3) + ki] = f2bf(src[k * 64 + col]);
    }
  }
}

// stage one gathered f32 row chunk (4 floats) into a swizzled bf16 LDS tile
__device__ __forceinline__ float4 stage_row(char* tileBase, int r, int c4,
                                            const float* srcRow) {
  float4 v = *((const float4*)srcRow + c4);
  unsigned long long pk =
      (unsigned long long)f2bf(v.x) | ((unsigned long long)f2bf(v.y) << 16) |
      ((unsigned long long)f2bf(v.z) << 32) | ((unsigned long long)f2bf(v.w) << 48);
  *(unsigned long long*)(tileBase + r * 128 + SW(r, c4 * 8)) = pk;
  return v;
}

__device__ __forceinline__ s16x8 ldA(const char* tile, int ktLocal, int lane) {
  int r = lane & 15, kg = lane >> 4;
  int b = ktLocal * 64 + kg * 16;
  return *(const s16x8*)(tile + r * 128 + SW(r, b));
}

__device__ __forceinline__ s16x8 ldB(const unsigned short* wt, int base,
                                     int ktGlobal, int kg, int col) {
  return *(const s16x8*)(wt + base + (((ktGlobal * 4 + kg) * 64 + col) << 3));
}

// 4 block types x 1024 M-tiles, CONTIGUOUS ranges (type = bid >> 10):
// A={stop,fatt}, B={nfatt}, C={bond}, D={nfrag hA+einsum}.
// Layer-2 heads use TRANSPOSED MFMA (swap A/B operands -> C[h][m]):
// reduction over h = 4 in-lane FMAs + 2 shuffles (vs 16 shuffles).
__global__ __launch_bounds__(256, 8) void decoder_main(
    const float* __restrict__ flf, const float* __restrict__ flnf,
    const float* __restrict__ gsf, const float* __restrict__ hpart,
    const float* __restrict__ hfoc,
    const int* __restrict__ nidx, const int* __restrict__ faidx,
    const int* __restrict__ naidx,
    const float* __restrict__ stopB1, const float* __restrict__ stopW2,
    const float* __restrict__ stopB2,
    const float* __restrict__ fattB1, const float* __restrict__ fattW2,
    const float* __restrict__ fattB2,
    const float* __restrict__ nfragB1, const float* __restrict__ nfragW2,
    const float* __restrict__ nfragB2,
    const float* __restrict__ nfattB1, const float* __restrict__ nfattW2,
    const float* __restrict__ nfattB2,
    const float* __restrict__ bondB1, const float* __restrict__ bondW2,
    const float* __restrict__ bondB2,
    const float* __restrict__ hB4, const unsigned short* __restrict__ wt,
    float* __restrict__ out) {
  const int tid = threadIdx.x;
  const int lane = tid & 63;
  const int w = tid >> 6;             // wave: owns h strip [16w, 16w+16)
  const int kg = lane >> 4;           // k-group 0..3
  const int cl = lane & 15;
  const int col = w * 16 + cl;        // weight column for ldB
  const int hb = w * 16 + kg * 4;     // this lane's 4 h indices (transposed C)
  const int bid = (int)blockIdx.x;
  const int type = bid >> 10;         // contiguous: L1 keeps one type's weights
  const int m0 = (bid & 1023) * 16;

  float* o_stop = out;                 // [MG]
  float* o_nfrag = out + MG;           // [MG,64]
  float* o_fatt = out + MG + MG * 64;  // [3*MG]
  float* o_nfatt = o_fatt + NFOC;      // [4*MG]
  float* o_bond = o_nfatt + NNXT;      // [MG,4]

  __shared__ char tiles[14336];     // up to 7 bf16 tiles (16 x 128B, swizzled)
  __shared__ float hAl[16][68];     // type D only
  __shared__ float scp[4][4][16];   // [wave][slot][graph] partial h-sums
  char* TG = tiles;                 // xg
  char* TP = tiles + 2048;          // xp
  char* T2 = tiles + 4096;          // A: hf[3] | B/C: xf
  char* T3 = tiles + 6144;          // B: na[4] | C: pooled

  // ---------------- stage (per type) ----------------
  {
    int r = tid >> 4, c4 = tid & 15;
    int m = m0 + r;
    stage_row(TG, r, c4, gsf + (size_t)m * 64);
    if (type == 0) {
#pragma unroll
      for (int rr = 0; rr < 3; ++rr)
        stage_row(T2 + rr * 2048, r, c4, hfoc + (size_t)(m + rr * MG) * 64);
    } else if (type == 1) {
      stage_row(TP, r, c4, hpart + (size_t)faidx[m] * 64);
      stage_row(T2, r, c4, flf + (size_t)nidx[m] * 64);
#pragma unroll
      for (int rr = 0; rr < 4; ++rr)
        stage_row(T3 + rr * 2048, r, c4, flnf + (size_t)naidx[m + rr * MG] * 64);
    } else if (type == 2) {
      stage_row(TP, r, c4, hpart + (size_t)faidx[m] * 64);
      stage_row(T2, r, c4, flf + (size_t)nidx[m] * 64);
      float px = 0.f, py = 0.f, pz = 0.f, pw = 0.f;
#pragma unroll
      for (int rr = 0; rr < 4; ++rr) {
        float4 v = *((const float4*)(flnf + (size_t)naidx[m + rr * MG] * 64) + c4);
        px += v.x; py += v.y; pz += v.z; pw += v.w;
      }
      unsigned long long pk = (unsigned long long)f2bf(0.25f * px) |
                              ((unsigned long long)f2bf(0.25f * py) << 16) |
                              ((unsigned long long)f2bf(0.25f * pz) << 32) |
                              ((unsigned long long)f2bf(0.25f * pw) << 48);
      *(unsigned long long*)(T3 + r * 128 + SW(r, c4 * 8)) = pk;
    } else {
      stage_row(TP, r, c4, hpart + (size_t)faidx[m] * 64);
    }
  }
  __syncthreads();

#define MFMA(a, b, c) __builtin_amdgcn_mfma_f32_16x16x32_bf16(a, b, c, 0, 0, 0)
// transposed-head reduce: v holds per-lane partial; sum over kg groups.
#define REDT(v, slot)                                                      \
  {                                                                        \
    v += __shfl_xor(v, 16);                                                \
    v += __shfl_xor(v, 32);                                                \
    if (lane < 16) scp[w][slot][lane] = v;                                 \
  }

  if (type == 0) {
    // ---------------- stop (K=64) -> slot 0 [transposed] ----------------
    {
      f32x4 acc = *(const f32x4*)(stopB1 + hb);
      acc = MFMA(ldB(wt, WT_STOP, 0, kg, col), ldA(TG, 0, lane), acc);
      acc = MFMA(ldB(wt, WT_STOP, 1, kg, col), ldA(TG, 1, lane), acc);
      f32x4 w2 = *(const f32x4*)(stopW2 + hb);
      float v = 0.f;
#pragma unroll
      for (int i = 0; i < 4; ++i) v = fmaf(lrelu(acc[i]), w2[i], v);
      REDT(v, 0);
    }
    // ---------------- fatt (shared K=64 + 3 x K=64) -> slots 1..3 ----------
    {
      f32x4 aS = *(const f32x4*)(fattB1 + hb);
      aS = MFMA(ldB(wt, WT_FATT, 0, kg, col), ldA(TG, 0, lane), aS);
      aS = MFMA(ldB(wt, WT_FATT, 1, kg, col), ldA(TG, 1, lane), aS);
      f32x4 w2 = *(const f32x4*)(fattW2 + hb);
#pragma unroll
      for (int rr = 0; rr < 3; ++rr) {
        f32x4 acc = aS;
        acc = MFMA(ldB(wt, WT_FATT, 2, kg, col), ldA(T2 + rr * 2048, 0, lane), acc);
        acc = MFMA(ldB(wt, WT_FATT, 3, kg, col), ldA(T2 + rr * 2048, 1, lane), acc);
        float v = 0.f;
#pragma unroll
        for (int i = 0; i < 4; ++i) v = fmaf(lrelu(acc[i]), w2[i], v);
        REDT(v, 1 + rr);
      }
    }
    __syncthreads();
    if (tid < 32) {
      int mm = tid & 15;
      int m = m0 + mm;
      if (tid < 16) {
        float s = scp[0][0][mm] + scp[1][0][mm] + scp[2][0][mm] + scp[3][0][mm];
        o_stop[m] = s + stopB2[0];
      } else {
        float sc[3];
#pragma unroll
        for (int r = 0; r < 3; ++r)
          sc[r] = scp[0][1 + r][mm] + scp[1][1 + r][mm] + scp[2][1 + r][mm] +
                  scp[3][1 + r][mm] + fattB2[0];
        float mx = fmaxf(fmaxf(sc[0], sc[1]), sc[2]);
        float e0 = expf(sc[0] - mx), e1 = expf(sc[1] - mx), e2 = expf(sc[2] - mx);
        float inv = 1.f / (e0 + e1 + e2);
        o_fatt[m] = e0 * inv;
        o_fatt[m + MG] = e1 * inv;
        o_fatt[m + 2 * MG] = e2 * inv;
      }
    }
  } else if (type == 1) {
    // ---------------- nfatt (shared K=192 + 4 x K=64) [transposed] ---------
    {
      f32x4 aS = *(const f32x4*)(nfattB1 + hb);
      aS = MFMA(ldB(wt, WT_NFATT, 0, kg, col), ldA(TG, 0, lane), aS);
      aS = MFMA(ldB(wt, WT_NFATT, 1, kg, col), ldA(TG, 1, lane), aS);
      aS = MFMA(ldB(wt, WT_NFATT, 2, kg, col), ldA(TP, 0, lane), aS);
      aS = MFMA(ldB(wt, WT_NFATT, 3, kg, col), ldA(TP, 1, lane), aS);
      aS = MFMA(ldB(wt, WT_NFATT, 4, kg, col), ldA(T2, 0, lane), aS);
      aS = MFMA(ldB(wt, WT_NFATT, 5, kg, col), ldA(T2, 1, lane), aS);
      f32x4 w2 = *(const f32x4*)(nfattW2 + hb);
#pragma unroll
      for (int rr = 0; rr < 4; ++rr) {
        f32x4 acc = aS;
        acc = MFMA(ldB(wt, WT_NFATT, 6, kg, col), ldA(T3 + rr * 2048, 0, lane), acc);
        acc = MFMA(ldB(wt, WT_NFATT, 7, kg, col), ldA(T3 + rr * 2048, 1, lane), acc);
        float v = 0.f;
#pragma unroll
        for (int i = 0; i < 4; ++i) v = fmaf(lrelu(acc[i]), w2[i], v);
        REDT(v, rr);
      }
    }
    __syncthreads();
    if (tid < 16) {
      int m = m0 + tid;
      float sc[4];
#pragma unroll
      for (int r = 0; r < 4; ++r)
        sc[r] = scp[0][r][tid] + scp[1][r][tid] + scp[2][r][tid] +
                scp[3][r][tid] + nfattB2[0];
      float mx = fmaxf(fmaxf(sc[0], sc[1]), fmaxf(sc[2], sc[3]));
      float e0 = expf(sc[0] - mx), e1 = expf(sc[1] - mx), e2 = expf(sc[2] - mx),
            e3 = expf(sc[3] - mx);
      float inv = 1.f / (e0 + e1 + e2 + e3);
      o_nfatt[m] = e0 * inv;
      o_nfatt[m + MG] = e1 * inv;
      o_nfatt[m + 2 * MG] = e2 * inv;
      o_nfatt[m + 3 * MG] = e3 * inv;
    }
  } else if (type == 2) {
    // ---------------- bond (K=256) [transposed] ----------------
    {
      f32x4 acc = *(const f32x4*)(bondB1 + hb);
      acc = MFMA(ldB(wt, WT_BOND, 0, kg, col), ldA(TG, 0, lane), acc);
      acc = MFMA(ldB(wt, WT_BOND, 1, kg, col), ldA(TG, 1, lane), acc);
      acc = MFMA(ldB(wt, WT_BOND, 2, kg, col), ldA(TP, 0, lane), acc);
      acc = MFMA(ldB(wt, WT_BOND, 3, kg, col), ldA(TP, 1, lane), acc);
      acc = MFMA(ldB(wt, WT_BOND, 4, kg, col), ldA(T2, 0, lane), acc);
      acc = MFMA(ldB(wt, WT_BOND, 5, kg, col), ldA(T2, 1, lane), acc);
      acc = MFMA(ldB(wt, WT_BOND, 6, kg, col), ldA(T3, 0, lane), acc);
      acc = MFMA(ldB(wt, WT_BOND, 7, kg, col), ldA(T3, 1, lane), acc);
      float l4[4];
      f32x4 bw[4];
#pragma unroll
      for (int i = 0; i < 4; ++i) {
        l4[i] = lrelu(acc[i]);
        bw[i] = *(const f32x4*)(bondW2 + (hb + i) * 4);
      }
#pragma unroll
      for (int o = 0; o < 4; ++o) {
        float v = 0.f;
#pragma unroll
        for (int i = 0; i < 4; ++i) v = fmaf(l4[i], bw[i][o], v);
        REDT(v, o);
      }
    }
    __syncthreads();
    if (tid < 16) {
      int m = m0 + tid;
#pragma unroll
      for (int o = 0; o < 4; ++o) {
        float s = scp[0][o][tid] + scp[1][o][tid] + scp[2][o][tid] +
                  scp[3][o][tid];
        o_bond[m * 4 + o] = s + bondB2[o];
      }
    }
  } else {
    // ---------------- nfrag hA (K=128, normal orientation) + einsum --------
    {
      float b1 = nfragB1[col];
      f32x4 acc = {b1, b1, b1, b1};
      acc = MFMA(ldA(TG, 0, lane), ldB(wt, WT_NFRAG, 0, kg, col), acc);
      acc = MFMA(ldA(TG, 1, lane), ldB(wt, WT_NFRAG, 1, kg, col), acc);
      acc = MFMA(ldA(TP, 0, lane), ldB(wt, WT_NFRAG, 2, kg, col), acc);
      acc = MFMA(ldA(TP, 1, lane), ldB(wt, WT_NFRAG, 3, kg, col), acc);
#pragma unroll
      for (int i = 0; i < 4; ++i) hAl[kg * 4 + i][col] = acc[i];
    }
    __syncthreads();
    // out[m,l] = sum_h lrelu(hA[m,h]+hB[h,l])*w2[h]; lane = l
    {
      float accL[4] = {0.f, 0.f, 0.f, 0.f};
#pragma unroll
      for (int hg = 0; hg < 16; ++hg) {
        f32x4 hb4v = *(const f32x4*)(hB4 + hg * 256 + lane * 4);
        f32x4 w2v = *(const f32x4*)(nfragW2 + hg * 4);
#pragma unroll
        for (int mi = 0; mi < 4; ++mi) {
          f32x4 ha = *(const f32x4*)(&hAl[w * 4 + mi][hg * 4]);  // uniform b128
#pragma unroll
          for (int j = 0; j < 4; ++j) {
            float x = ha[j] + hb4v[j];
            accL[mi] = fmaf(fmaxf(x, 0.01f * x), w2v[j], accL[mi]);
          }
        }
      }
#pragma unroll
      for (int mi = 0; mi < 4; ++mi)
        o_nfrag[(size_t)(m0 + w * 4 + mi) * 64 + lane] = accL[mi] + nfragB2[0];
    }
  }
}

extern "C" void kernel_launch(void* const* d_in, const int* in_sizes, int n_in,
                              void* d_out, int out_size, void* d_ws, size_t ws_size,
                              hipStream_t stream) {
  const float* flf = (const float*)d_in[0];
  const float* flnf = (const float*)d_in[1];
  const float* gsf = (const float*)d_in[2];
  const float* hpart = (const float*)d_in[3];
  const float* hfoc = (const float*)d_in[4];
  const int* nidx = (const int*)d_in[5];
  const int* faidx = (const int*)d_in[9];
  const int* naidx = (const int*)d_in[10];

  const float* stopW1 = (const float*)d_in[13];
  const float* stopB1 = (const float*)d_in[14];
  const float* stopW2 = (const float*)d_in[15];
  const float* stopB2 = (const float*)d_in[16];
  const float* fattW1 = (const float*)d_in[17];
  const float* fattB1 = (const float*)d_in[18];
  const float* fattW2 = (const float*)d_in[19];
  const float* fattB2 = (const float*)d_in[20];
  const float* nfragW1 = (const float*)d_in[21];
  const float* nfragB1 = (const float*)d_in[22];
  const float* nfragW2 = (const float*)d_in[23];
  const float* nfragB2 = (const float*)d_in[24];
  const float* nfattW1 = (const float*)d_in[25];
  const float* nfattB1 = (const float*)d_in[26];
  const float* nfattW2 = (const float*)d_in[27];
  const float* nfattB2 = (const float*)d_in[28];
  const float* bondW1 = (const float*)d_in[29];
  const float* bondB1 = (const float*)d_in[30];
  const float* bondW2 = (const float*)d_in[31];
  const float* bondB2 = (const float*)d_in[32];

  float* hB4 = (float*)d_ws;                                     // 16 KB
  unsigned short* wtb = (unsigned short*)((char*)d_ws + 16384);  // 104 KB

  prep<<<16 + (WT_TOTAL + 255) / 256, 256, 0, stream>>>(
      flf, stopW1, fattW1, nfragW1, nfattW1, bondW1, hB4, wtb);

  decoder_main<<<4 * 1024, 256, 0, stream>>>(
      flf, flnf, gsf, hpart, hfoc, nidx, faidx, naidx,
      stopB1, stopW2, stopB2,
      fattB1, fattW2, fattB2,
      nfragB1, nfragW2, nfragB2,
      nfattB1, nfattW2, nfattB2,
      bondB1, bondW2, bondB2,
      hB4, wtb, (float*)d_out);
}

// Round 11
// 25.320 us; speedup vs baseline: 1.4426x; 1.0546x over previous
//
#include <hip/hip_runtime.h>
#include <math.h>

#define MG 16384
#define NFOC (3 * MG)
#define NNXT (4 * MG)

typedef float f32x4 __attribute__((ext_vector_type(4)));
typedef short s16x8 __attribute__((ext_vector_type(8)));

// ws layout: hB4 f32[4096] at byte 0 (layout [h>>2][l][h&3]); bf16 weight frags
// (ushort) at byte 16384. per-MLP bases in SHORTS within wt region:
#define WT_STOP 0
#define WT_FATT 4096
#define WT_NFRAG 12288
#define WT_NFATT 20480
#define WT_BOND 36864
#define WT_TOTAL 53248  // shorts

#define SW(r, b) ((b) ^ (((r) & 7) << 4))

// NOTE: DPP 16-lane reduction (R5/R7) QUARANTINED (absmax 11.58).
// v_cvt_pk_bf16_f32 inline asm also quarantined. __shfl_xor is proven.
// R9 lesson: block-type interleaving thrashes per-CU L1 -> contiguous ranges.
// R11: types B (nfatt) and C (bond) merged -- they gather identical rows;
// pooled feats built from stage_row's returned f32 (bit-identical to R10).

__device__ __forceinline__ float lrelu(float x) { return x > 0.f ? x : 0.01f * x; }

__device__ __forceinline__ unsigned short f2bf(float f) {
  union { float f; unsigned u; } a;
  a.f = f;
  unsigned u = a.u;
  unsigned r = (u + 0x7fffu + ((u >> 16) & 1u)) >> 16;  // RNE
  return (unsigned short)r;
}

// ---------------- prep: hB4 (f32) + weight transpose/convert to B-frag layout
__global__ void prep(const float* __restrict__ flf,
                     const float* __restrict__ stopW1,
                     const float* __restrict__ fattW1,
                     const float* __restrict__ nfragW1,
                     const float* __restrict__ nfattW1,
                     const float* __restrict__ bondW1,
                     float* __restrict__ hB4, unsigned short* __restrict__ wt) {
  int b = blockIdx.x, t = threadIdx.x;
  if (b < 16) {  // hB[h,l] = sum_k flf[l][k]*nfragW1[(128+k)*64+h]
    int l = b * 4 + (t >> 6), h = t & 63;
    float acc = 0.f;
#pragma unroll 8
    for (int k = 0; k < 64; ++k)
      acc = fmaf(flf[l * 64 + k], nfragW1[(128 + k) * 64 + h], acc);
    hB4[(h >> 2) * 256 + l * 4 + (h & 3)] = acc;
  } else {
    int e = (b - 16) * 256 + t;  // 0..53247
    if (e < WT_TOTAL) {
      int k_all = e >> 6, col = e & 63;
      const float* src;
      int k, base;
      if (k_all < 64) { src = stopW1; k = k_all; base = WT_STOP; }
      else if (k_all < 192) { src = fattW1; k = k_all - 64; base = WT_FATT; }
      else if (k_all < 320) { src = nfragW1; k = k_all - 192; base = WT_NFRAG; }
      else if (k_all < 576) { src = nfattW1; k = k_all - 320; base = WT_NFATT; }
      else { src = bondW1; k = k_all - 576; base = WT_BOND; }
      int kt = k >> 5, kg = (k >> 3) & 3, ki = k & 7;
      wt[base + (((kt * 4 + kg) * 64 + col) << 3) + ki] = f2bf(src[k * 64 + col]);
    }
  }
}

// stage one gathered f32 row chunk (4 floats) into a swizzled bf16 LDS tile
__device__ __forceinline__ float4 stage_row(char* tileBase, int r, int c4,
                                            const float* srcRow) {
  float4 v = *((const float4*)srcRow + c4);
  unsigned long long pk =
      (unsigned long long)f2bf(v.x) | ((unsigned long long)f2bf(v.y) << 16) |
      ((unsigned long long)f2bf(v.z) << 32) | ((unsigned long long)f2bf(v.w) << 48);
  *(unsigned long long*)(tileBase + r * 128 + SW(r, c4 * 8)) = pk;
  return v;
}

__device__ __forceinline__ s16x8 ldA(const char* tile, int ktLocal, int lane) {
  int r = lane & 15, kg = lane >> 4;
  int b = ktLocal * 64 + kg * 16;
  return *(const s16x8*)(tile + r * 128 + SW(r, b));
}

__device__ __forceinline__ s16x8 ldB(const unsigned short* wt, int base,
                                     int ktGlobal, int kg, int col) {
  return *(const s16x8*)(wt + base + (((ktGlobal * 4 + kg) * 64 + col) << 3));
}

// 3 block types x 1024 M-tiles, CONTIGUOUS ranges (type = bid >> 10):
// A={stop,fatt}, BC={nfatt+bond merged}, D={nfrag hA+einsum}.
// Layer-2 heads use TRANSPOSED MFMA (C[h][m]): reduce = 4 FMA + 2 shuffles.
__global__ __launch_bounds__(256, 8) void decoder_main(
    const float* __restrict__ flf, const float* __restrict__ flnf,
    const float* __restrict__ gsf, const float* __restrict__ hpart,
    const float* __restrict__ hfoc,
    const int* __restrict__ nidx, const int* __restrict__ faidx,
    const int* __restrict__ naidx,
    const float* __restrict__ stopB1, const float* __restrict__ stopW2,
    const float* __restrict__ stopB2,
    const float* __restrict__ fattB1, const float* __restrict__ fattW2,
    const float* __restrict__ fattB2,
    const float* __restrict__ nfragB1, const float* __restrict__ nfragW2,
    const float* __restrict__ nfragB2,
    const float* __restrict__ nfattB1, const float* __restrict__ nfattW2,
    const float* __restrict__ nfattB2,
    const float* __restrict__ bondB1, const float* __restrict__ bondW2,
    const float* __restrict__ bondB2,
    const float* __restrict__ hB4, const unsigned short* __restrict__ wt,
    float* __restrict__ out) {
  const int tid = threadIdx.x;
  const int lane = tid & 63;
  const int w = tid >> 6;             // wave: owns h strip [16w, 16w+16)
  const int kg = lane >> 4;           // k-group 0..3
  const int cl = lane & 15;
  const int col = w * 16 + cl;        // weight column for ldB
  const int hb = w * 16 + kg * 4;     // this lane's 4 h indices (transposed C)
  const int bid = (int)blockIdx.x;
  const int type = bid >> 10;         // contiguous: L1 keeps one type's weights
  const int m0 = (bid & 1023) * 16;

  float* o_stop = out;                 // [MG]
  float* o_nfrag = out + MG;           // [MG,64]
  float* o_fatt = out + MG + MG * 64;  // [3*MG]
  float* o_nfatt = o_fatt + NFOC;      // [4*MG]
  float* o_bond = o_nfatt + NNXT;      // [MG,4]

  __shared__ char tiles[16384];    // 8 bf16 tiles (16 x 128B, swizzled)
  __shared__ float scp[4][8][16];  // [wave][slot][graph] partial h-sums
  char* TG = tiles;                // xg
  char* TP = tiles + 2048;         // xp
  char* T2 = tiles + 4096;         // A: hf[0] | BC: xf
  char* T3 = tiles + 6144;         // A: hf[1,2] | BC: na[4]
  char* TPOOL = tiles + 14336;     // BC: pooled na mean
  float (*hAl)[68] = (float(*)[68])(tiles + 4096);  // D overlay (4352 B)

  // ---------------- stage (per type) ----------------
  {
    int r = tid >> 4, c4 = tid & 15;
    int m = m0 + r;
    stage_row(TG, r, c4, gsf + (size_t)m * 64);
    if (type == 0) {
      stage_row(T2, r, c4, hfoc + (size_t)m * 64);
#pragma unroll
      for (int rr = 1; rr < 3; ++rr)
        stage_row(T3 + (rr - 1) * 2048, r, c4, hfoc + (size_t)(m + rr * MG) * 64);
    } else if (type == 1) {
      stage_row(TP, r, c4, hpart + (size_t)faidx[m] * 64);
      stage_row(T2, r, c4, flf + (size_t)nidx[m] * 64);
      float px = 0.f, py = 0.f, pz = 0.f, pw = 0.f;
#pragma unroll
      for (int rr = 0; rr < 4; ++rr) {
        float4 v = stage_row(T3 + rr * 2048, r, c4,
                             flnf + (size_t)naidx[m + rr * MG] * 64);
        px += v.x; py += v.y; pz += v.z; pw += v.w;
      }
      unsigned long long pk = (unsigned long long)f2bf(0.25f * px) |
                              ((unsigned long long)f2bf(0.25f * py) << 16) |
                              ((unsigned long long)f2bf(0.25f * pz) << 32) |
                              ((unsigned long long)f2bf(0.25f * pw) << 48);
      *(unsigned long long*)(TPOOL + r * 128 + SW(r, c4 * 8)) = pk;
    } else {
      stage_row(TP, r, c4, hpart + (size_t)faidx[m] * 64);
    }
  }
  __syncthreads();

#define MFMA(a, b, c) __builtin_amdgcn_mfma_f32_16x16x32_bf16(a, b, c, 0, 0, 0)
// transposed-head reduce: v holds per-lane partial; sum over kg groups.
#define REDT(v, slot)                                                      \
  {                                                                        \
    v += __shfl_xor(v, 16);                                                \
    v += __shfl_xor(v, 32);                                                \
    if (lane < 16) scp[w][slot][lane] = v;                                 \
  }

  if (type == 0) {
    // ---------------- stop (K=64) -> slot 0 [transposed] ----------------
    s16x8 aTG0 = ldA(TG, 0, lane), aTG1 = ldA(TG, 1, lane);
    {
      f32x4 acc = *(const f32x4*)(stopB1 + hb);
      acc = MFMA(ldB(wt, WT_STOP, 0, kg, col), aTG0, acc);
      acc = MFMA(ldB(wt, WT_STOP, 1, kg, col), aTG1, acc);
      f32x4 w2 = *(const f32x4*)(stopW2 + hb);
      float v = 0.f;
#pragma unroll
      for (int i = 0; i < 4; ++i) v = fmaf(lrelu(acc[i]), w2[i], v);
      REDT(v, 0);
    }
    // ---------------- fatt (shared K=64 + 3 x K=64) -> slots 1..3 ----------
    {
      f32x4 aS = *(const f32x4*)(fattB1 + hb);
      aS = MFMA(ldB(wt, WT_FATT, 0, kg, col), aTG0, aS);
      aS = MFMA(ldB(wt, WT_FATT, 1, kg, col), aTG1, aS);
      f32x4 w2 = *(const f32x4*)(fattW2 + hb);
#pragma unroll
      for (int rr = 0; rr < 3; ++rr) {
        char* THF = (rr == 0) ? T2 : T3 + (rr - 1) * 2048;
        f32x4 acc = aS;
        acc = MFMA(ldB(wt, WT_FATT, 2, kg, col), ldA(THF, 0, lane), acc);
        acc = MFMA(ldB(wt, WT_FATT, 3, kg, col), ldA(THF, 1, lane), acc);
        float v = 0.f;
#pragma unroll
        for (int i = 0; i < 4; ++i) v = fmaf(lrelu(acc[i]), w2[i], v);
        REDT(v, 1 + rr);
      }
    }
    __syncthreads();
    if (tid < 32) {
      int mm = tid & 15;
      int m = m0 + mm;
      if (tid < 16) {
        float s = scp[0][0][mm] + scp[1][0][mm] + scp[2][0][mm] + scp[3][0][mm];
        o_stop[m] = s + stopB2[0];
      } else {
        float sc[3];
#pragma unroll
        for (int r = 0; r < 3; ++r)
          sc[r] = scp[0][1 + r][mm] + scp[1][1 + r][mm] + scp[2][1 + r][mm] +
                  scp[3][1 + r][mm] + fattB2[0];
        float mx = fmaxf(fmaxf(sc[0], sc[1]), sc[2]);
        float e0 = expf(sc[0] - mx), e1 = expf(sc[1] - mx), e2 = expf(sc[2] - mx);
        float inv = 1.f / (e0 + e1 + e2);
        o_fatt[m] = e0 * inv;
        o_fatt[m + MG] = e1 * inv;
        o_fatt[m + 2 * MG] = e2 * inv;
      }
    }
  } else if (type == 1) {
    // ------- merged nfatt (slots 0..3) + bond (slots 4..7) [transposed] ----
    // shared ldA fragments loaded once, used by both heads
    s16x8 aTG0 = ldA(TG, 0, lane), aTG1 = ldA(TG, 1, lane);
    s16x8 aTP0 = ldA(TP, 0, lane), aTP1 = ldA(TP, 1, lane);
    s16x8 aT20 = ldA(T2, 0, lane), aT21 = ldA(T2, 1, lane);
    {
      f32x4 aS = *(const f32x4*)(nfattB1 + hb);
      aS = MFMA(ldB(wt, WT_NFATT, 0, kg, col), aTG0, aS);
      aS = MFMA(ldB(wt, WT_NFATT, 1, kg, col), aTG1, aS);
      aS = MFMA(ldB(wt, WT_NFATT, 2, kg, col), aTP0, aS);
      aS = MFMA(ldB(wt, WT_NFATT, 3, kg, col), aTP1, aS);
      aS = MFMA(ldB(wt, WT_NFATT, 4, kg, col), aT20, aS);
      aS = MFMA(ldB(wt, WT_NFATT, 5, kg, col), aT21, aS);
      f32x4 w2 = *(const f32x4*)(nfattW2 + hb);
#pragma unroll
      for (int rr = 0; rr < 4; ++rr) {
        f32x4 acc = aS;
        acc = MFMA(ldB(wt, WT_NFATT, 6, kg, col), ldA(T3 + rr * 2048, 0, lane), acc);
        acc = MFMA(ldB(wt, WT_NFATT, 7, kg, col), ldA(T3 + rr * 2048, 1, lane), acc);
        float v = 0.f;
#pragma unroll
        for (int i = 0; i < 4; ++i) v = fmaf(lrelu(acc[i]), w2[i], v);
        REDT(v, rr);
      }
    }
    {
      f32x4 acc = *(const f32x4*)(bondB1 + hb);
      acc = MFMA(ldB(wt, WT_BOND, 0, kg, col), aTG0, acc);
      acc = MFMA(ldB(wt, WT_BOND, 1, kg, col), aTG1, acc);
      acc = MFMA(ldB(wt, WT_BOND, 2, kg, col), aTP0, acc);
      acc = MFMA(ldB(wt, WT_BOND, 3, kg, col), aTP1, acc);
      acc = MFMA(ldB(wt, WT_BOND, 4, kg, col), aT20, acc);
      acc = MFMA(ldB(wt, WT_BOND, 5, kg, col), aT21, acc);
      acc = MFMA(ldB(wt, WT_BOND, 6, kg, col), ldA(TPOOL, 0, lane), acc);
      acc = MFMA(ldB(wt, WT_BOND, 7, kg, col), ldA(TPOOL, 1, lane), acc);
      float l4[4];
      f32x4 bw[4];
#pragma unroll
      for (int i = 0; i < 4; ++i) {
        l4[i] = lrelu(acc[i]);
        bw[i] = *(const f32x4*)(bondW2 + (hb + i) * 4);
      }
#pragma unroll
      for (int o = 0; o < 4; ++o) {
        float v = 0.f;
#pragma unroll
        for (int i = 0; i < 4; ++i) v = fmaf(l4[i], bw[i][o], v);
        REDT(v, 4 + o);
      }
    }
    __syncthreads();
    if (tid < 32) {
      int mm = tid & 15;
      int m = m0 + mm;
      if (tid < 16) {
        float sc[4];
#pragma unroll
        for (int r = 0; r < 4; ++r)
          sc[r] = scp[0][r][mm] + scp[1][r][mm] + scp[2][r][mm] +
                  scp[3][r][mm] + nfattB2[0];
        float mx = fmaxf(fmaxf(sc[0], sc[1]), fmaxf(sc[2], sc[3]));
        float e0 = expf(sc[0] - mx), e1 = expf(sc[1] - mx),
              e2 = expf(sc[2] - mx), e3 = expf(sc[3] - mx);
        float inv = 1.f / (e0 + e1 + e2 + e3);
        o_nfatt[m] = e0 * inv;
        o_nfatt[m + MG] = e1 * inv;
        o_nfatt[m + 2 * MG] = e2 * inv;
        o_nfatt[m + 3 * MG] = e3 * inv;
      } else {
#pragma unroll
        for (int o = 0; o < 4; ++o) {
          float s = scp[0][4 + o][mm] + scp[1][4 + o][mm] + scp[2][4 + o][mm] +
                    scp[3][4 + o][mm];
          o_bond[m * 4 + o] = s + bondB2[o];
        }
      }
    }
  } else {
    // ---------------- nfrag hA (K=128, normal orientation) + einsum --------
    {
      float b1 = nfragB1[col];
      f32x4 acc = {b1, b1, b1, b1};
      acc = MFMA(ldA(TG, 0, lane), ldB(wt, WT_NFRAG, 0, kg, col), acc);
      acc = MFMA(ldA(TG, 1, lane), ldB(wt, WT_NFRAG, 1, kg, col), acc);
      acc = MFMA(ldA(TP, 0, lane), ldB(wt, WT_NFRAG, 2, kg, col), acc);
      acc = MFMA(ldA(TP, 1, lane), ldB(wt, WT_NFRAG, 3, kg, col), acc);
      __syncthreads();  // hAl overlays T2: all ldA reads done before write
#pragma unroll
      for (int i = 0; i < 4; ++i) hAl[kg * 4 + i][col] = acc[i];
    }
    __syncthreads();
    // out[m,l] = sum_h lrelu(hA[m,h]+hB[h,l])*w2[h]; lane = l
    {
      float accL[4] = {0.f, 0.f, 0.f, 0.f};
#pragma unroll
      for (int hg = 0; hg < 16; ++hg) {
        f32x4 hb4v = *(const f32x4*)(hB4 + hg * 256 + lane * 4);
        f32x4 w2v = *(const f32x4*)(nfragW2 + hg * 4);
#pragma unroll
        for (int mi = 0; mi < 4; ++mi) {
          f32x4 ha = *(const f32x4*)(&hAl[w * 4 + mi][hg * 4]);  // uniform b128
#pragma unroll
          for (int j = 0; j < 4; ++j) {
            float x = ha[j] + hb4v[j];
            accL[mi] = fmaf(fmaxf(x, 0.01f * x), w2v[j], accL[mi]);
          }
        }
      }
#pragma unroll
      for (int mi = 0; mi < 4; ++mi)
        o_nfrag[(size_t)(m0 + w * 4 + mi) * 64 + lane] = accL[mi] + nfragB2[0];
    }
  }
}

extern "C" void kernel_launch(void* const* d_in, const int* in_sizes, int n_in,
                              void* d_out, int out_size, void* d_ws, size_t ws_size,
                              hipStream_t stream) {
  const float* flf = (const float*)d_in[0];
  const float* flnf = (const float*)d_in[1];
  const float* gsf = (const float*)d_in[2];
  const float* hpart = (const float*)d_in[3];
  const float* hfoc = (const float*)d_in[4];
  const int* nidx = (const int*)d_in[5];
  const int* faidx = (const int*)d_in[9];
  const int* naidx = (const int*)d_in[10];

  const float* stopW1 = (const float*)d_in[13];
  const float* stopB1 = (const float*)d_in[14];
  const float* stopW2 = (const float*)d_in[15];
  const float* stopB2 = (const float*)d_in[16];
  const float* fattW1 = (const float*)d_in[17];
  const float* fattB1 = (const float*)d_in[18];
  const float* fattW2 = (const float*)d_in[19];
  const float* fattB2 = (const float*)d_in[20];
  const float* nfragW1 = (const float*)d_in[21];
  const float* nfragB1 = (const float*)d_in[22];
  const float* nfragW2 = (const float*)d_in[23];
  const float* nfragB2 = (const float*)d_in[24];
  const float* nfattW1 = (const float*)d_in[25];
  const float* nfattB1 = (const float*)d_in[26];
  const float* nfattW2 = (const float*)d_in[27];
  const float* nfattB2 = (const float*)d_in[28];
  const float* bondW1 = (const float*)d_in[29];
  const float* bondB1 = (const float*)d_in[30];
  const float* bondW2 = (const float*)d_in[31];
  const float* bondB2 = (const float*)d_in[32];

  float* hB4 = (float*)d_ws;                                     // 16 KB
  unsigned short* wtb = (unsigned short*)((char*)d_ws + 16384);  // 104 KB

  prep<<<16 + (WT_TOTAL + 255) / 256, 256, 0, stream>>>(
      flf, stopW1, fattW1, nfragW1, nfattW1, bondW1, hB4, wtb);

  decoder_main<<<3 * 1024, 256, 0, stream>>>(
      flf, flnf, gsf, hpart, hfoc, nidx, faidx, naidx,
      stopB1, stopW2, stopB2,
      fattB1, fattW2, fattB2,
      nfragB1, nfragW2, nfragB2,
      nfattB1, nfattW2, nfattB2,
      bondB1, bondW2, bondB2,
      hB4, wtb, (float*)d_out);
}